// Round 6
// baseline (651.176 us; speedup 1.0000x reference)
//
#include <hip/hip_runtime.h>
#include <stdint.h>

// out[i] = max((cnts[g_i] + hist_slot[g_i]) / (total + N), 0.01),
//   g_i = gdict[i], hist_slot[s] = #{ t : gdict[flatten_label[t]] == s }.
//
// Strategy (round 6): per-XCD L2-privatized histograms.
// Plain atomicAdd is device-scope (memory-side write-through, ~32B/op; round-1
// measured 641us for 16.7M of them). Workgroup-scope atomics execute at the
// issuing XCD's local L2 (TCC). Each XCD gets a PRIVATE copy of the histogram
// (2MB << 4MB L2), indexed by s_getreg(HW_REG_XCC_ID) [m09: returns 0..7], so
// copy k is only ever touched by XCD k -> single-L2 residency, atomicity at
// that L2, and the kernel-end L2 flush publishes results to the next kernel.
// This deletes the counting sort entirely (round-5: ~145MB of sort traffic).

#define NXCD 8

__device__ __forceinline__ uint32_t xcc_id() {
    uint32_t x;
    asm("s_getreg_b32 %0, hwreg(HW_REG_XCC_ID)" : "=s"(x));
    return x & (NXCD - 1);
}

__device__ __forceinline__ void atom_add_local(uint32_t* p, uint32_t v) {
    // workgroup scope -> no sc1 -> executes at the local XCD's L2
    __hip_atomic_fetch_add(p, v, __ATOMIC_RELAXED, __HIP_MEMORY_SCOPE_WORKGROUP);
}

// ---- K1: label histogram, one private copy per XCD ----
__global__ __launch_bounds__(256) void k1_hist(const int* __restrict__ labels,
                                               uint32_t* __restrict__ hist8, // [NXCD][llen]
                                               int n, int llen) {
    uint32_t* h = hist8 + (size_t)xcc_id() * llen;
    int tid = blockIdx.x * 256 + threadIdx.x;
    int stride = gridDim.x * 256;
    int n4 = n >> 2;
    const int4* l4 = (const int4*)labels;
    for (int i = tid; i < n4; i += stride) {
        int4 v = l4[i];
        atom_add_local(&h[v.x], 1u);
        atom_add_local(&h[v.y], 1u);
        atom_add_local(&h[v.z], 1u);
        atom_add_local(&h[v.w], 1u);
    }
    for (int i = (n4 << 2) + tid; i < n; i += stride)
        atom_add_local(&h[labels[i]], 1u);
}

// ---- K2: fold label-space histogram through gdict into slot space,
//          again into per-XCD private copies (local-L2 atomics) ----
__global__ __launch_bounds__(256) void k2_fold(const uint32_t* __restrict__ hist8,
                                               const int* __restrict__ gdict,
                                               uint32_t* __restrict__ slot8, // [NXCD][nbins]
                                               int llen, int nbins) {
    int l = blockIdx.x * 256 + threadIdx.x;
    if (l >= llen) return;
    uint32_t sum = 0;
    #pragma unroll
    for (int x = 0; x < NXCD; ++x)
        sum += hist8[(size_t)x * llen + l];     // 8 independent coalesced streams
    if (sum) {
        uint32_t g = (uint32_t)gdict[l];
        if (g < (uint32_t)nbins)
            atom_add_local(&slot8[(size_t)xcc_id() * nbins + g], sum);
    }
}

// ---- K3: gather 8 slot copies, normalize, clip ----
__global__ __launch_bounds__(256) void k3_out(const int* __restrict__ gdict,
                                              const float* __restrict__ cnts,
                                              const uint32_t* __restrict__ slot8,
                                              const float* __restrict__ total,
                                              float* __restrict__ out, int llen,
                                              int nbins, float nf) {
    int i = blockIdx.x * 256 + threadIdx.x;
    if (i >= llen) return;
    uint32_t g = (uint32_t)gdict[i];
    uint32_t s = 0;
    #pragma unroll
    for (int x = 0; x < NXCD; ++x)
        s += slot8[(size_t)x * nbins + g];
    float c = cnts[g] + (float)s;
    out[i] = fmaxf(c / (total[0] + nf), 0.01f);
}

// ---- fallback: direct device-scope atomics (correct everywhere) ----
__global__ void hist_atomic(const int* __restrict__ labels,
                            const int* __restrict__ gdict,
                            unsigned int* __restrict__ ws, int n) {
    int tid = blockIdx.x * blockDim.x + threadIdx.x;
    int stride = gridDim.x * blockDim.x;
    int n4 = n >> 2;
    const int4* l4 = (const int4*)labels;
    for (int i = tid; i < n4; i += stride) {
        int4 v = l4[i];
        atomicAdd(&ws[gdict[v.x]], 1u);
        atomicAdd(&ws[gdict[v.y]], 1u);
        atomicAdd(&ws[gdict[v.z]], 1u);
        atomicAdd(&ws[gdict[v.w]], 1u);
    }
    for (int i = (n4 << 2) + tid; i < n; i += stride)
        atomicAdd(&ws[gdict[labels[i]]], 1u);
}

__global__ __launch_bounds__(256) void p5_simple(const int* __restrict__ gdict,
                                                 const float* __restrict__ cnts,
                                                 const uint32_t* __restrict__ slotsum,
                                                 const float* __restrict__ total,
                                                 float* __restrict__ out, int llen, float nf) {
    int i = blockIdx.x * 256 + threadIdx.x;
    if (i < llen) {
        uint32_t g = (uint32_t)gdict[i];
        float c = cnts[g] + (float)slotsum[g];
        out[i] = fmaxf(c / (total[0] + nf), 0.01f);
    }
}

static inline size_t align256(size_t x) { return (x + 255) & ~(size_t)255; }

extern "C" void kernel_launch(void* const* d_in, const int* in_sizes, int n_in,
                              void* d_out, int out_size, void* d_ws, size_t ws_size,
                              hipStream_t stream) {
    const int* gdict   = (const int*)d_in[0];
    const int* labels  = (const int*)d_in[1];
    const float* cnts  = (const float*)d_in[3];
    const float* total = (const float*)d_in[4];
    float* out = (float*)d_out;

    int llen  = in_sizes[0];
    int n     = in_sizes[1];
    int nbins = in_sizes[3];

    // ws layout: [slot8: NXCD*nbins*4][hist8: NXCD*llen*4], one memset covers both
    size_t o_slot8 = 0;
    size_t o_hist8 = align256((size_t)NXCD * nbins * 4);
    size_t needed  = o_hist8 + (size_t)NXCD * llen * 4;

    uint8_t* ws8 = (uint8_t*)d_ws;

    if (needed <= ws_size) {
        uint32_t* slot8 = (uint32_t*)(ws8 + o_slot8);
        uint32_t* hist8 = (uint32_t*)(ws8 + o_hist8);

        hipMemsetAsync(ws8, 0, needed, stream);   // zero both copies (44.8 MB)
        hipLaunchKernelGGL(k1_hist, dim3(2048), dim3(256), 0, stream,
                           labels, hist8, n, llen);
        hipLaunchKernelGGL(k2_fold, dim3((llen + 255) / 256), dim3(256), 0, stream,
                           hist8, gdict, slot8, llen, nbins);
        hipLaunchKernelGGL(k3_out, dim3((llen + 255) / 256), dim3(256), 0, stream,
                           gdict, cnts, slot8, total, out, llen, nbins, (float)n);
    } else {
        uint32_t* slotsum = (uint32_t*)ws8;
        hipMemsetAsync(slotsum, 0, (size_t)nbins * 4, stream);
        hipLaunchKernelGGL(hist_atomic, dim3(2048), dim3(256), 0, stream,
                           labels, gdict, (unsigned int*)slotsum, n);
        hipLaunchKernelGGL(p5_simple, dim3((llen + 255) / 256), dim3(256), 0, stream,
                           gdict, cnts, slotsum, total, out, llen, (float)n);
    }
}

// Round 7
// 59.829 us; speedup vs baseline: 10.8839x; 10.8839x over previous
//
#include <hip/hip_runtime.h>
#include <stdint.h>

// out[i] = max((cnts[g_i] + hist_slot[g_i]) / (total + N), 0.01),
//   g_i = gdict[i], hist_slot[s] = #{ t : gdict[flatten_label[t]] == s }.
//
// hist_slot[s] = sum_{l : gdict[l]==s} hist_label[l] -> hot pass never touches
// gdict. Round-6 lesson: gfx950 global atomics are memory-side at ANY scope
// (workgroup-scope atomicAdd still wrote 524MB through) -> the only fast fold
// is an atomic-FREE one. Winner-marking: marker[g]=l+1 (plain store), losers
// set conflicted[g]=1; unconflicted outputs read their own ltot[i] directly;
// only conflicted labels (normally none) use device atomics.

#define CHUNK   8192
#define FBITS   12
#define FW      4096      // fine bins per coarse bucket
#define SPLIT   16        // chunk-range splits per bucket in p4a
#define SE_MAX  256       // max chunks per p4a block
#define PA_T    512
#define PER_T   (CHUNK / PA_T)   // 16 labels staged in registers per thread

static inline size_t align256(size_t x) { return (x + 255) & ~(size_t)255; }

// ---- pA: per-chunk LDS counting sort by coarse bucket (label>>12) ----
__global__ __launch_bounds__(PA_T) void pa_sort(const int* __restrict__ labels,
                                                uint32_t* __restrict__ cstart, // [nchunks][nbuck+1]
                                                uint16_t* __restrict__ sorted, // [nchunks][CHUNK]
                                                int n, int nbuck) {
    __shared__ uint16_t srt[CHUNK];     // 16 KB
    __shared__ uint32_t cnt[256];
    __shared__ uint32_t scan[PA_T];
    __shared__ uint32_t cur[257];
    int tid = threadIdx.x;
    int bk  = blockIdx.x;
    int base = bk * CHUNK;

    uint32_t v[PER_T];
    if (tid < 256) cnt[tid] = 0;
    __syncthreads();

    int tb = base + tid * PER_T;
    if (tb + PER_T <= n) {
        const int4* l4 = (const int4*)(labels + tb);
        #pragma unroll
        for (int i = 0; i < PER_T / 4; ++i) {
            int4 q = l4[i];
            v[4*i+0] = (uint32_t)q.x; v[4*i+1] = (uint32_t)q.y;
            v[4*i+2] = (uint32_t)q.z; v[4*i+3] = (uint32_t)q.w;
        }
        #pragma unroll
        for (int i = 0; i < PER_T; ++i) atomicAdd(&cnt[v[i] >> FBITS], 1u);
    } else {
        for (int i = 0; i < PER_T; ++i) {
            int idx = tb + i;
            if (idx < n) {
                v[i] = (uint32_t)labels[idx];
                atomicAdd(&cnt[v[i] >> FBITS], 1u);
            } else v[i] = 0xFFFFFFFFu;
        }
    }
    __syncthreads();

    // exclusive scan of 256 counters
    uint32_t c = (tid < 256) ? cnt[tid] : 0u;
    scan[tid] = c;
    __syncthreads();
    for (int d = 1; d < 256; d <<= 1) {
        uint32_t add = (tid >= d) ? scan[tid - d] : 0u;
        __syncthreads();
        scan[tid] += add;
        __syncthreads();
    }
    if (tid < 256) cur[tid] = scan[tid] - c;
    if (tid == 255) cur[256] = scan[255];
    __syncthreads();

    for (int i = tid; i < nbuck + 1; i += PA_T)
        cstart[(size_t)bk * (nbuck + 1) + i] = cur[i];
    __syncthreads();   // cstart row must be written out before cursors mutate

    #pragma unroll
    for (int i = 0; i < PER_T; ++i) {
        uint32_t val = v[i];
        if (val != 0xFFFFFFFFu) {
            uint32_t p = atomicAdd(&cur[val >> FBITS], 1u);
            srt[p] = (uint16_t)(val & (FW - 1));
        }
    }
    __syncthreads();

    int4* dst = (int4*)(sorted + (size_t)bk * CHUNK);
    const int4* src = (const int4*)srt;
    for (int k = tid; k < (CHUNK * 2) / 16; k += PA_T)
        dst[k] = src[k];
}

// ---- p4a: partial fine histogram per (bucket, chunk-range); also writes
//      the winner marker (marker[g] = l+1, plain store, last-writer-wins) ----
__global__ __launch_bounds__(256) void p4a(const uint16_t* __restrict__ sorted,
                                           const uint32_t* __restrict__ cstart,
                                           uint8_t* __restrict__ partials, // [nbuck*SPLIT][FW]
                                           const int* __restrict__ gdict,
                                           uint32_t* __restrict__ marker,  // [llen]
                                           int llen, int nbins,
                                           int nchunks, int nbuck, int cpb) {
    __shared__ uint32_t h[FW];          // 16 KB
    __shared__ uint32_t se0[SE_MAX];
    __shared__ uint32_t se1[SE_MAX];
    int tid = threadIdx.x;

    // winner marking (independent of histogram work; fire early)
    for (int l = blockIdx.x * 256 + tid; l < llen; l += gridDim.x * 256) {
        uint32_t g = (uint32_t)gdict[l];
        if (g < (uint32_t)nbins) marker[g] = (uint32_t)l + 1u;
    }

    int B = blockIdx.x / SPLIT;
    int k = blockIdx.x % SPLIT;
    for (int j = tid; j < FW; j += 256) h[j] = 0;

    int c0 = k * cpb;
    int c1 = min(c0 + cpb, nchunks);
    int m = c1 - c0;
    for (int t = tid; t < m; t += 256) {
        const uint32_t* row = cstart + (size_t)(c0 + t) * (nbuck + 1);
        se0[t] = row[B];
        se1[t] = row[B + 1];
    }
    __syncthreads();

    int wave = tid >> 6, lane = tid & 63;
    int u = wave;
    for (; u + 4 < m; u += 8) {
        uint32_t sA = se0[u],     eA = se1[u];
        uint32_t sB = se0[u + 4], eB = se1[u + 4];
        const uint16_t* segA = sorted + (size_t)(c0 + u) * CHUNK;
        const uint16_t* segB = sorted + (size_t)(c0 + u + 4) * CHUNK;
        uint32_t iA = sA + lane, iB = sB + lane;
        uint16_t vA = 0, vB = 0;
        bool okA = iA < eA, okB = iB < eB;
        if (okA) vA = segA[iA];
        if (okB) vB = segB[iB];
        if (okA) atomicAdd(&h[vA], 1u);
        if (okB) atomicAdd(&h[vB], 1u);
        for (iA += 64; iA < eA; iA += 64) atomicAdd(&h[segA[iA]], 1u);
        for (iB += 64; iB < eB; iB += 64) atomicAdd(&h[segB[iB]], 1u);
    }
    for (; u < m; u += 4) {
        uint32_t s = se0[u], e = se1[u];
        const uint16_t* seg = sorted + (size_t)(c0 + u) * CHUNK;
        for (uint32_t i = s + lane; i < e; i += 64)
            atomicAdd(&h[seg[i]], 1u);
    }
    __syncthreads();

    uint8_t* dst = partials + (size_t)blockIdx.x * FW;
    for (int j = tid; j < FW; j += 256) dst[j] = (uint8_t)h[j];
}

// ---- K3: per-label total + conflict detection (losers mark conflicted) ----
__global__ __launch_bounds__(256) void k3_detect(const uint8_t* __restrict__ partials,
                                                 const int* __restrict__ gdict,
                                                 const uint32_t* __restrict__ marker,
                                                 uint32_t* __restrict__ ltot,     // [llen]
                                                 uint8_t* __restrict__ conflicted,// [nbins]
                                                 int llen, int nbins) {
    int l = blockIdx.x * 256 + threadIdx.x;
    if (l >= llen) return;
    int B = l >> FBITS;
    int j = l & (FW - 1);
    const uint8_t* p = partials + (size_t)B * SPLIT * FW + j;
    uint32_t sum = 0;
    #pragma unroll
    for (int k = 0; k < SPLIT; ++k) sum += p[(size_t)k * FW];
    ltot[l] = sum;
    uint32_t g = (uint32_t)gdict[l];
    if (g < (uint32_t)nbins) {
        if (marker[g] != (uint32_t)l + 1u) conflicted[g] = 1;  // benign race
    }
}

// ---- K4: fold ONLY conflicted labels with device atomics (normally zero) ----
__global__ __launch_bounds__(256) void k4_fold(const uint32_t* __restrict__ ltot,
                                               const int* __restrict__ gdict,
                                               const uint8_t* __restrict__ conflicted,
                                               uint32_t* __restrict__ slotsum,
                                               int llen, int nbins) {
    int l = blockIdx.x * 256 + threadIdx.x;
    if (l >= llen) return;
    uint32_t g = (uint32_t)gdict[l];
    if (g < (uint32_t)nbins && conflicted[g])
        atomicAdd(&slotsum[g], ltot[l]);
}

// ---- K5: epilogue ----
__global__ __launch_bounds__(256) void k5_out(const int* __restrict__ gdict,
                                              const float* __restrict__ cnts,
                                              const uint32_t* __restrict__ ltot,
                                              const uint8_t* __restrict__ conflicted,
                                              const uint32_t* __restrict__ slotsum,
                                              const float* __restrict__ total,
                                              float* __restrict__ out,
                                              int llen, int nbins, float nf) {
    int i = blockIdx.x * 256 + threadIdx.x;
    if (i >= llen) return;
    uint32_t g = (uint32_t)gdict[i];
    float c = 0.0f;
    if (g < (uint32_t)nbins) {
        uint32_t v = conflicted[g] ? slotsum[g] : ltot[i];
        c = cnts[g] + (float)v;
    }
    out[i] = fmaxf(c / (total[0] + nf), 0.01f);
}

// ---- fallback: direct device-scope atomics ----
__global__ void hist_atomic(const int* __restrict__ labels,
                            const int* __restrict__ gdict,
                            unsigned int* __restrict__ ws, int n) {
    int tid = blockIdx.x * blockDim.x + threadIdx.x;
    int stride = gridDim.x * blockDim.x;
    int n4 = n >> 2;
    const int4* l4 = (const int4*)labels;
    for (int i = tid; i < n4; i += stride) {
        int4 v = l4[i];
        atomicAdd(&ws[gdict[v.x]], 1u);
        atomicAdd(&ws[gdict[v.y]], 1u);
        atomicAdd(&ws[gdict[v.z]], 1u);
        atomicAdd(&ws[gdict[v.w]], 1u);
    }
    for (int i = (n4 << 2) + tid; i < n; i += stride)
        atomicAdd(&ws[gdict[labels[i]]], 1u);
}

__global__ __launch_bounds__(256) void p5_simple(const int* __restrict__ gdict,
                                                 const float* __restrict__ cnts,
                                                 const uint32_t* __restrict__ slotsum,
                                                 const float* __restrict__ total,
                                                 float* __restrict__ out, int llen, float nf) {
    int i = blockIdx.x * 256 + threadIdx.x;
    if (i < llen) {
        uint32_t g = (uint32_t)gdict[i];
        float c = cnts[g] + (float)slotsum[g];
        out[i] = fmaxf(c / (total[0] + nf), 0.01f);
    }
}

extern "C" void kernel_launch(void* const* d_in, const int* in_sizes, int n_in,
                              void* d_out, int out_size, void* d_ws, size_t ws_size,
                              hipStream_t stream) {
    const int* gdict   = (const int*)d_in[0];
    const int* labels  = (const int*)d_in[1];
    const float* cnts  = (const float*)d_in[3];
    const float* total = (const float*)d_in[4];
    float* out = (float*)d_out;

    int llen  = in_sizes[0];
    int n     = in_sizes[1];
    int nbins = in_sizes[3];

    int nchunks = (n + CHUNK - 1) / CHUNK;
    int nbuck   = (llen + FW - 1) >> FBITS;
    int cpb     = (nchunks + SPLIT - 1) / SPLIT;

    // ws layout: [slotsum][marker][conflicted] (one zero-fill) [ltot][cstart][sorted][partials]
    size_t o_slot = 0;
    size_t o_mark = align256(o_slot + (size_t)nbins * 4);
    size_t o_conf = align256(o_mark + (size_t)llen * 4);
    size_t o_ltot = align256(o_conf + (size_t)nbins);
    size_t o_cst  = align256(o_ltot + (size_t)llen * 4);
    size_t o_sort = align256(o_cst  + (size_t)nchunks * (nbuck + 1) * 4);
    size_t o_part = align256(o_sort + (size_t)nchunks * CHUNK * 2);
    size_t needed = o_part + (size_t)nbuck * SPLIT * FW;

    uint8_t* ws8 = (uint8_t*)d_ws;

    if (nbuck <= 256 && cpb <= SE_MAX && needed <= ws_size) {
        uint32_t* slotsum    = (uint32_t*)(ws8 + o_slot);
        uint32_t* marker     = (uint32_t*)(ws8 + o_mark);
        uint8_t*  conflicted = (uint8_t*)(ws8 + o_conf);
        uint32_t* ltot       = (uint32_t*)(ws8 + o_ltot);
        uint32_t* cstart     = (uint32_t*)(ws8 + o_cst);
        uint16_t* sorted     = (uint16_t*)(ws8 + o_sort);
        uint8_t*  partials   = (uint8_t*)(ws8 + o_part);

        // zero slotsum + marker + conflicted in one fill (marker sentinel = 0,
        // writers store l+1, so 0 means "no contributor")
        hipMemsetAsync(ws8, 0, o_ltot, stream);
        hipLaunchKernelGGL(pa_sort, dim3(nchunks), dim3(PA_T), 0, stream,
                           labels, cstart, sorted, n, nbuck);
        hipLaunchKernelGGL(p4a, dim3(nbuck * SPLIT), dim3(256), 0, stream,
                           sorted, cstart, partials, gdict, marker,
                           llen, nbins, nchunks, nbuck, cpb);
        hipLaunchKernelGGL(k3_detect, dim3((llen + 255) / 256), dim3(256), 0, stream,
                           partials, gdict, marker, ltot, conflicted, llen, nbins);
        hipLaunchKernelGGL(k4_fold, dim3((llen + 255) / 256), dim3(256), 0, stream,
                           ltot, gdict, conflicted, slotsum, llen, nbins);
        hipLaunchKernelGGL(k5_out, dim3((llen + 255) / 256), dim3(256), 0, stream,
                           gdict, cnts, ltot, conflicted, slotsum, total, out,
                           llen, nbins, (float)n);
    } else {
        uint32_t* slotsum = (uint32_t*)ws8;
        hipMemsetAsync(slotsum, 0, (size_t)nbins * 4, stream);
        hipLaunchKernelGGL(hist_atomic, dim3(2048), dim3(256), 0, stream,
                           labels, gdict, (unsigned int*)slotsum, n);
        hipLaunchKernelGGL(p5_simple, dim3((llen + 255) / 256), dim3(256), 0, stream,
                           gdict, cnts, slotsum, total, out, llen, (float)n);
    }
}

// Round 8
// 53.949 us; speedup vs baseline: 12.0702x; 1.1090x over previous
//
#include <hip/hip_runtime.h>
#include <stdint.h>

// out[i] = max((cnts[g_i] + hist_slot[g_i]) / (total + N), 0.01),
//   g_i = gdict[i], hist_slot[s] = #{ t : gdict[flatten_label[t]] == s }.
//
// hist_slot[s] = sum_{l: gdict[l]==s} hist_label[l] -> hot path never gathers
// gdict. gfx950 facts driving the design:
//  - global atomics are memory-side write-through (~32B each) at ANY scope
//    (round 1: 16.7M = 641us; round 6: workgroup-scope identical) -> hot path
//    must be LDS-atomic only.
//  - LDS atomic issue ~2/cyc/CU -> each 16.7M-atomic pass ~11-13us. Round 5-7
//    used 3 passes; this version uses 2 (fixed-stride partition: no counting
//    pass, no scan; cursor-end = count; rare overflow -> ovf[] device atomic).
//  - ws poison fills show 256MiB -> 83MB layout is safe (guarded anyway).

#define CHUNK   8192
#define FBITS   12
#define FW      4096
#define SLOT    128        // fixed slots per (chunk,bucket); Poisson(67)+7.5sigma
#define SPLIT   16
#define SE_MAX  256
#define NBUCK_MAX 256

static inline size_t align256(size_t x) { return (x + 255) & ~(size_t)255; }

// ======================= v6 hot path =======================

// pa_fs: fixed-stride LDS partition. ONE LDS-atomic pass per label.
__global__ __launch_bounds__(512) void pa_fs(const int* __restrict__ labels,
                                             uint16_t* __restrict__ sorted, // [nchunks][nbuck][SLOT]
                                             uint8_t*  __restrict__ cnt8,   // [nbuck][nchunks]
                                             uint32_t* __restrict__ ovf,    // [llen]
                                             int n, int nbuck, int nchunks) {
    extern __shared__ uint16_t srt[];          // nbuck*SLOT u16
    __shared__ uint32_t cur[NBUCK_MAX];
    int tid = threadIdx.x, bk = blockIdx.x;
    int base = bk * CHUNK;
    int m = min(CHUNK, n - base);

    for (int b = tid; b < nbuck; b += 512) cur[b] = (uint32_t)b * SLOT;
    __syncthreads();

    const int4* l4 = (const int4*)(labels + base);
    int k4n = m >> 2;
    for (int k = tid; k < k4n; k += 512) {
        int4 q = l4[k];
        uint32_t v0 = (uint32_t)q.x, v1 = (uint32_t)q.y;
        uint32_t v2 = (uint32_t)q.z, v3 = (uint32_t)q.w;
        uint32_t b0 = v0 >> FBITS, b1 = v1 >> FBITS, b2 = v2 >> FBITS, b3 = v3 >> FBITS;
        uint32_t p0 = atomicAdd(&cur[b0], 1u);
        uint32_t p1 = atomicAdd(&cur[b1], 1u);
        uint32_t p2 = atomicAdd(&cur[b2], 1u);
        uint32_t p3 = atomicAdd(&cur[b3], 1u);
        if (p0 < (b0 + 1u) * SLOT) srt[p0] = (uint16_t)(v0 & (FW - 1)); else atomicAdd(&ovf[v0], 1u);
        if (p1 < (b1 + 1u) * SLOT) srt[p1] = (uint16_t)(v1 & (FW - 1)); else atomicAdd(&ovf[v1], 1u);
        if (p2 < (b2 + 1u) * SLOT) srt[p2] = (uint16_t)(v2 & (FW - 1)); else atomicAdd(&ovf[v2], 1u);
        if (p3 < (b3 + 1u) * SLOT) srt[p3] = (uint16_t)(v3 & (FW - 1)); else atomicAdd(&ovf[v3], 1u);
    }
    for (int i = (k4n << 2) + tid; i < m; i += 512) {
        uint32_t v = (uint32_t)labels[base + i];
        uint32_t b = v >> FBITS;
        uint32_t p = atomicAdd(&cur[b], 1u);
        if (p < (b + 1u) * SLOT) srt[p] = (uint16_t)(v & (FW - 1)); else atomicAdd(&ovf[v], 1u);
    }
    __syncthreads();

    // coalesced write-out of the whole fixed-stride region (garbage past each
    // cursor is never read: p4a_fs bounds by cnt8)
    int4* dst = (int4*)(sorted + (size_t)bk * nbuck * SLOT);
    const int4* src = (const int4*)srt;
    int nv = nbuck * (SLOT * 2 / 16);
    for (int k = tid; k < nv; k += 512) dst[k] = src[k];
    for (int b = tid; b < nbuck; b += 512) {
        uint32_t c = cur[b] - (uint32_t)b * SLOT;
        cnt8[(size_t)b * nchunks + bk] = (uint8_t)min(c, (uint32_t)SLOT);
    }
}

// p4a_fs: per-(bucket, chunk-range) fine histogram over fixed-stride cells.
// u32-paired reads (1 load covers 2 entries), LDS atomics, u8 partials.
// Also writes the winner marker (plain store, last-writer-wins).
__global__ __launch_bounds__(256) void p4a_fs(const uint16_t* __restrict__ sorted,
                                              const uint8_t* __restrict__ cnt8,
                                              uint8_t* __restrict__ partials, // [nbuck*SPLIT][FW]
                                              const int* __restrict__ gdict,
                                              uint32_t* __restrict__ marker,  // [nbins]
                                              int llen, int nbins,
                                              int nchunks, int nbuck, int cpb) {
    __shared__ uint32_t h[FW];          // 16 KB
    __shared__ uint8_t cn[SE_MAX];
    int tid = threadIdx.x;

    for (int l = blockIdx.x * 256 + tid; l < llen; l += gridDim.x * 256) {
        uint32_t g = (uint32_t)gdict[l];
        if (g < (uint32_t)nbins) marker[g] = (uint32_t)l + 1u;
    }

    int B = blockIdx.x / SPLIT;
    int k = blockIdx.x % SPLIT;
    for (int j = tid; j < FW; j += 256) h[j] = 0;

    int c0 = k * cpb;
    int c1 = min(c0 + cpb, nchunks);
    int m = c1 - c0;
    for (int t = tid; t < m; t += 256)
        cn[t] = cnt8[(size_t)B * nchunks + c0 + t];   // bucket-major: coalesced
    __syncthreads();

    int wave = tid >> 6, lane = tid & 63;
    int e0 = 2 * lane;
    int u = wave;
    for (; u + 4 < m; u += 8) {
        int lA = cn[u], lB = cn[u + 4];
        const uint32_t* sA = (const uint32_t*)(sorted + ((size_t)(c0 + u) * nbuck + B) * SLOT);
        const uint32_t* sB = (const uint32_t*)(sorted + ((size_t)(c0 + u + 4) * nbuck + B) * SLOT);
        uint32_t wA = 0, wB = 0;
        bool aA = e0 < lA, aB = e0 < lB;
        if (aA) wA = sA[lane];
        if (aB) wB = sB[lane];
        if (aA) { atomicAdd(&h[wA & 0xFFFFu], 1u); if (e0 + 1 < lA) atomicAdd(&h[wA >> 16], 1u); }
        if (aB) { atomicAdd(&h[wB & 0xFFFFu], 1u); if (e0 + 1 < lB) atomicAdd(&h[wB >> 16], 1u); }
    }
    for (; u < m; u += 4) {
        int len = cn[u];
        const uint32_t* s = (const uint32_t*)(sorted + ((size_t)(c0 + u) * nbuck + B) * SLOT);
        if (e0 < len) {
            uint32_t w = s[lane];
            atomicAdd(&h[w & 0xFFFFu], 1u);
            if (e0 + 1 < len) atomicAdd(&h[w >> 16], 1u);
        }
    }
    __syncthreads();

    uint8_t* dst = partials + (size_t)blockIdx.x * FW;
    for (int j = tid; j < FW; j += 256) dst[j] = (uint8_t)h[j];
}

// k3: per-label total (+rare overflow), losers fold into slotsum (atomics only
// on actually-colliding gdict entries; zero when gdict is injective).
__global__ __launch_bounds__(256) void k3_fold(const uint8_t* __restrict__ partials,
                                               const uint32_t* __restrict__ ovf,
                                               const int* __restrict__ gdict,
                                               const uint32_t* __restrict__ marker,
                                               uint32_t* __restrict__ ltot,      // [llen]
                                               uint8_t* __restrict__ conflicted, // [nbins]
                                               uint32_t* __restrict__ slotsum,   // [nbins]
                                               int llen, int nbins) {
    int l = blockIdx.x * 256 + threadIdx.x;
    if (l >= llen) return;
    int B = l >> FBITS;
    int j = l & (FW - 1);
    const uint8_t* p = partials + (size_t)B * SPLIT * FW + j;
    uint32_t sum = ovf[l];
    #pragma unroll
    for (int k = 0; k < SPLIT; ++k) sum += p[(size_t)k * FW];
    ltot[l] = sum;
    uint32_t g = (uint32_t)gdict[l];
    if (g < (uint32_t)nbins && marker[g] != (uint32_t)l + 1u) {
        conflicted[g] = 1;                    // benign same-value race
        atomicAdd(&slotsum[g], sum);          // losers only
    }
}

// k5: epilogue. Unconflicted slot -> its unique contributor is i itself;
// conflicted -> losers' slotsum + winner's ltot (order-independent sum).
__global__ __launch_bounds__(256) void k5_out(const int* __restrict__ gdict,
                                              const float* __restrict__ cnts,
                                              const uint32_t* __restrict__ ltot,
                                              const uint8_t* __restrict__ conflicted,
                                              const uint32_t* __restrict__ slotsum,
                                              const uint32_t* __restrict__ marker,
                                              const float* __restrict__ total,
                                              float* __restrict__ out,
                                              int llen, int nbins, float nf) {
    int i = blockIdx.x * 256 + threadIdx.x;
    if (i >= llen) return;
    uint32_t g = (uint32_t)gdict[i];
    float c = 0.0f;
    if (g < (uint32_t)nbins) {
        uint32_t v = conflicted[g] ? (slotsum[g] + ltot[marker[g] - 1u]) : ltot[i];
        c = cnts[g] + (float)v;
    }
    out[i] = fmaxf(c / (total[0] + nf), 0.01f);
}

// ======================= tier-2: proven round-5 path (57us) =======================

#define PA_T 512
#define PER_T (CHUNK / PA_T)

__global__ __launch_bounds__(PA_T) void pa_sort(const int* __restrict__ labels,
                                                uint32_t* __restrict__ cstart,
                                                uint16_t* __restrict__ sorted,
                                                int n, int nbuck) {
    __shared__ uint16_t srt[CHUNK];
    __shared__ uint32_t cnt[256];
    __shared__ uint32_t scan[PA_T];
    __shared__ uint32_t cur[257];
    int tid = threadIdx.x, bk = blockIdx.x;
    int base = bk * CHUNK;
    uint32_t v[PER_T];
    if (tid < 256) cnt[tid] = 0;
    __syncthreads();
    int tb = base + tid * PER_T;
    if (tb + PER_T <= n) {
        const int4* l4 = (const int4*)(labels + tb);
        #pragma unroll
        for (int i = 0; i < PER_T / 4; ++i) {
            int4 q = l4[i];
            v[4*i+0] = (uint32_t)q.x; v[4*i+1] = (uint32_t)q.y;
            v[4*i+2] = (uint32_t)q.z; v[4*i+3] = (uint32_t)q.w;
        }
        #pragma unroll
        for (int i = 0; i < PER_T; ++i) atomicAdd(&cnt[v[i] >> FBITS], 1u);
    } else {
        for (int i = 0; i < PER_T; ++i) {
            int idx = tb + i;
            if (idx < n) { v[i] = (uint32_t)labels[idx]; atomicAdd(&cnt[v[i] >> FBITS], 1u); }
            else v[i] = 0xFFFFFFFFu;
        }
    }
    __syncthreads();
    uint32_t c = (tid < 256) ? cnt[tid] : 0u;
    scan[tid] = c;
    __syncthreads();
    for (int d = 1; d < 256; d <<= 1) {
        uint32_t add = (tid >= d) ? scan[tid - d] : 0u;
        __syncthreads();
        scan[tid] += add;
        __syncthreads();
    }
    if (tid < 256) cur[tid] = scan[tid] - c;
    if (tid == 255) cur[256] = scan[255];
    __syncthreads();
    for (int i = tid; i < nbuck + 1; i += PA_T)
        cstart[(size_t)bk * (nbuck + 1) + i] = cur[i];
    __syncthreads();
    #pragma unroll
    for (int i = 0; i < PER_T; ++i) {
        uint32_t val = v[i];
        if (val != 0xFFFFFFFFu) {
            uint32_t p = atomicAdd(&cur[val >> FBITS], 1u);
            srt[p] = (uint16_t)(val & (FW - 1));
        }
    }
    __syncthreads();
    int4* dst = (int4*)(sorted + (size_t)bk * CHUNK);
    const int4* src = (const int4*)srt;
    for (int k = tid; k < (CHUNK * 2) / 16; k += PA_T) dst[k] = src[k];
}

__global__ __launch_bounds__(256) void p4a_c(const uint16_t* __restrict__ sorted,
                                             const uint32_t* __restrict__ cstart,
                                             uint8_t* __restrict__ partials,
                                             int nchunks, int nbuck, int cpb) {
    __shared__ uint32_t h[FW];
    __shared__ uint32_t se0[SE_MAX];
    __shared__ uint32_t se1[SE_MAX];
    int tid = threadIdx.x;
    int B = blockIdx.x / SPLIT;
    int k = blockIdx.x % SPLIT;
    for (int j = tid; j < FW; j += 256) h[j] = 0;
    int c0 = k * cpb, c1 = min(c0 + cpb, nchunks), m = c1 - c0;
    for (int t = tid; t < m; t += 256) {
        const uint32_t* row = cstart + (size_t)(c0 + t) * (nbuck + 1);
        se0[t] = row[B]; se1[t] = row[B + 1];
    }
    __syncthreads();
    int wave = tid >> 6, lane = tid & 63;
    int u = wave;
    for (; u + 4 < m; u += 8) {
        uint32_t sA = se0[u], eA = se1[u], sB = se0[u+4], eB = se1[u+4];
        const uint16_t* segA = sorted + (size_t)(c0 + u) * CHUNK;
        const uint16_t* segB = sorted + (size_t)(c0 + u + 4) * CHUNK;
        uint32_t iA = sA + lane, iB = sB + lane;
        uint16_t vA = 0, vB = 0;
        bool okA = iA < eA, okB = iB < eB;
        if (okA) vA = segA[iA];
        if (okB) vB = segB[iB];
        if (okA) atomicAdd(&h[vA], 1u);
        if (okB) atomicAdd(&h[vB], 1u);
        for (iA += 64; iA < eA; iA += 64) atomicAdd(&h[segA[iA]], 1u);
        for (iB += 64; iB < eB; iB += 64) atomicAdd(&h[segB[iB]], 1u);
    }
    for (; u < m; u += 4) {
        uint32_t s = se0[u], e = se1[u];
        const uint16_t* seg = sorted + (size_t)(c0 + u) * CHUNK;
        for (uint32_t i = s + lane; i < e; i += 64) atomicAdd(&h[seg[i]], 1u);
    }
    __syncthreads();
    uint8_t* dst = partials + (size_t)blockIdx.x * FW;
    for (int j = tid; j < FW; j += 256) dst[j] = (uint8_t)h[j];
}

__global__ __launch_bounds__(256) void p4b(const uint8_t* __restrict__ partials,
                                           const int* __restrict__ gdict,
                                           uint32_t* __restrict__ slotsum,
                                           int llen, int nbins) {
    int l = blockIdx.x * 256 + threadIdx.x;
    if (l >= llen) return;
    int B = l >> FBITS;
    int j = l & (FW - 1);
    const uint8_t* p = partials + (size_t)B * SPLIT * FW + j;
    uint32_t sum = 0;
    #pragma unroll
    for (int k = 0; k < SPLIT; ++k) sum += p[(size_t)k * FW];
    if (sum) {
        uint32_t g = (uint32_t)gdict[l];
        if (g < (uint32_t)nbins) atomicAdd(&slotsum[g], sum);
    }
}

__global__ __launch_bounds__(256) void p5_simple(const int* __restrict__ gdict,
                                                 const float* __restrict__ cnts,
                                                 const uint32_t* __restrict__ slotsum,
                                                 const float* __restrict__ total,
                                                 float* __restrict__ out, int llen, float nf) {
    int i = blockIdx.x * 256 + threadIdx.x;
    if (i < llen) {
        uint32_t g = (uint32_t)gdict[i];
        float c = cnts[g] + (float)slotsum[g];
        out[i] = fmaxf(c / (total[0] + nf), 0.01f);
    }
}

// ======================= tier-3: direct atomics =======================
__global__ void hist_atomic(const int* __restrict__ labels,
                            const int* __restrict__ gdict,
                            unsigned int* __restrict__ ws, int n) {
    int tid = blockIdx.x * blockDim.x + threadIdx.x;
    int stride = gridDim.x * blockDim.x;
    int n4 = n >> 2;
    const int4* l4 = (const int4*)labels;
    for (int i = tid; i < n4; i += stride) {
        int4 v = l4[i];
        atomicAdd(&ws[gdict[v.x]], 1u);
        atomicAdd(&ws[gdict[v.y]], 1u);
        atomicAdd(&ws[gdict[v.z]], 1u);
        atomicAdd(&ws[gdict[v.w]], 1u);
    }
    for (int i = (n4 << 2) + tid; i < n; i += stride)
        atomicAdd(&ws[gdict[labels[i]]], 1u);
}

extern "C" void kernel_launch(void* const* d_in, const int* in_sizes, int n_in,
                              void* d_out, int out_size, void* d_ws, size_t ws_size,
                              hipStream_t stream) {
    const int* gdict   = (const int*)d_in[0];
    const int* labels  = (const int*)d_in[1];
    const float* cnts  = (const float*)d_in[3];
    const float* total = (const float*)d_in[4];
    float* out = (float*)d_out;

    int llen  = in_sizes[0];
    int n     = in_sizes[1];
    int nbins = in_sizes[3];

    int nchunks = (n + CHUNK - 1) / CHUNK;
    int nbuck   = (llen + FW - 1) >> FBITS;
    int cpb     = (nchunks + SPLIT - 1) / SPLIT;

    uint8_t* ws8 = (uint8_t*)d_ws;

    // ---- v6 layout ----
    size_t o_slot = 0;
    size_t o_mark = align256(o_slot + (size_t)nbins * 4);
    size_t o_conf = align256(o_mark + (size_t)nbins * 4);
    size_t o_ovf  = align256(o_conf + (size_t)nbins);
    size_t o_ltot = align256(o_ovf  + (size_t)llen * 4);     // memset covers [0, o_ltot)
    size_t o_cnt  = align256(o_ltot + (size_t)llen * 4);
    size_t o_srt  = align256(o_cnt  + (size_t)nbuck * nchunks);
    size_t o_part = align256(o_srt  + (size_t)nchunks * nbuck * SLOT * 2);
    size_t need6  = o_part + (size_t)nbuck * SPLIT * FW;

    // ---- tier-2 layout ----
    size_t t_slot = 0;
    size_t t_cst  = align256((size_t)nbins * 4);
    size_t t_srt  = align256(t_cst + (size_t)nchunks * (nbuck + 1) * 4);
    size_t t_part = align256(t_srt + (size_t)nchunks * CHUNK * 2);
    size_t need5  = t_part + (size_t)nbuck * SPLIT * FW;

    size_t lds_fs = (size_t)nbuck * SLOT * 2;

    if (nbuck <= NBUCK_MAX && cpb <= SE_MAX && need6 <= ws_size && lds_fs <= 64 * 1024) {
        uint32_t* slotsum    = (uint32_t*)(ws8 + o_slot);
        uint32_t* marker     = (uint32_t*)(ws8 + o_mark);
        uint8_t*  conflicted = (uint8_t*)(ws8 + o_conf);
        uint32_t* ovf        = (uint32_t*)(ws8 + o_ovf);
        uint32_t* ltot       = (uint32_t*)(ws8 + o_ltot);
        uint8_t*  cnt8       = (uint8_t*)(ws8 + o_cnt);
        uint16_t* sorted     = (uint16_t*)(ws8 + o_srt);
        uint8_t*  partials   = (uint8_t*)(ws8 + o_part);

        hipMemsetAsync(ws8, 0, o_ltot, stream);  // slotsum+marker+conflicted+ovf
        hipLaunchKernelGGL(pa_fs, dim3(nchunks), dim3(512), lds_fs, stream,
                           labels, sorted, cnt8, ovf, n, nbuck, nchunks);
        hipLaunchKernelGGL(p4a_fs, dim3(nbuck * SPLIT), dim3(256), 0, stream,
                           sorted, cnt8, partials, gdict, marker,
                           llen, nbins, nchunks, nbuck, cpb);
        hipLaunchKernelGGL(k3_fold, dim3((llen + 255) / 256), dim3(256), 0, stream,
                           partials, ovf, gdict, marker, ltot, conflicted, slotsum,
                           llen, nbins);
        hipLaunchKernelGGL(k5_out, dim3((llen + 255) / 256), dim3(256), 0, stream,
                           gdict, cnts, ltot, conflicted, slotsum, marker, total,
                           out, llen, nbins, (float)n);
    } else if (nbuck <= 256 && cpb <= SE_MAX && need5 <= ws_size) {
        uint32_t* slotsum  = (uint32_t*)(ws8 + t_slot);
        uint32_t* cstart   = (uint32_t*)(ws8 + t_cst);
        uint16_t* sorted   = (uint16_t*)(ws8 + t_srt);
        uint8_t*  partials = (uint8_t*)(ws8 + t_part);

        hipMemsetAsync(slotsum, 0, (size_t)nbins * 4, stream);
        hipLaunchKernelGGL(pa_sort, dim3(nchunks), dim3(PA_T), 0, stream,
                           labels, cstart, sorted, n, nbuck);
        hipLaunchKernelGGL(p4a_c, dim3(nbuck * SPLIT), dim3(256), 0, stream,
                           sorted, cstart, partials, nchunks, nbuck, cpb);
        hipLaunchKernelGGL(p4b, dim3((llen + 255) / 256), dim3(256), 0, stream,
                           partials, gdict, slotsum, llen, nbins);
        hipLaunchKernelGGL(p5_simple, dim3((llen + 255) / 256), dim3(256), 0, stream,
                           gdict, cnts, slotsum, total, out, llen, (float)n);
    } else {
        uint32_t* slotsum = (uint32_t*)ws8;
        hipMemsetAsync(slotsum, 0, (size_t)nbins * 4, stream);
        hipLaunchKernelGGL(hist_atomic, dim3(2048), dim3(256), 0, stream,
                           labels, gdict, (unsigned int*)slotsum, n);
        hipLaunchKernelGGL(p5_simple, dim3((llen + 255) / 256), dim3(256), 0, stream,
                           gdict, cnts, slotsum, total, out, llen, (float)n);
    }
}

// Round 9
// 53.481 us; speedup vs baseline: 12.1758x; 1.0088x over previous
//
#include <hip/hip_runtime.h>
#include <stdint.h>

// out[i] = max((cnts[g_i] + hist_slot[g_i]) / (total + N), 0.01),
//   g_i = gdict[i], hist_slot[s] = #{ t : gdict[flatten_label[t]] == s }.
//
// hist_slot[s] = sum_{l: gdict[l]==s} hist_label[l] -> hot path never gathers
// gdict. gfx950 facts driving the design:
//  - global atomics are memory-side write-through (~32B each) at ANY scope
//    (round 1: 16.7M = 641us; round 6: workgroup-scope identical) -> hot path
//    must be LDS-atomic only.
//  - LDS atomic issue ~2/cyc/CU -> each 16.7M-atomic pass ~11-13us; this
//    pipeline uses exactly 2 such passes (fixed-stride partition, no scan).
//  - rocclr fillBufferAligned (hipMemsetAsync) runs a tiny fixed grid
//    (~250 GB/s, 8% occupancy) -> do our own zeroing with a grid-stride
//    kernel; and don't zero marker at all (in-image entries are always
//    rewritten by p4a_fs before k3/k5 read them).

#define CHUNK   8192
#define FBITS   12
#define FW      4096
#define SLOT    128        // fixed slots per (chunk,bucket); Poisson(67)+7.5sigma
#define SPLIT   16
#define SE_MAX  256
#define NBUCK_MAX 256

static inline size_t align256(size_t x) { return (x + 255) & ~(size_t)255; }

// ---- zero_ws: grid-stride int4 zero of [0, bytes16*16) ----
__global__ __launch_bounds__(256) void zero_ws(int4* __restrict__ p, int n16) {
    int tid = blockIdx.x * 256 + threadIdx.x;
    int stride = gridDim.x * 256;
    int4 z = {0, 0, 0, 0};
    for (int i = tid; i < n16; i += stride) p[i] = z;
}

// ======================= v6 hot path =======================

// pa_fs: fixed-stride LDS partition. ONE LDS-atomic pass per label.
__global__ __launch_bounds__(512) void pa_fs(const int* __restrict__ labels,
                                             uint16_t* __restrict__ sorted, // [nchunks][nbuck][SLOT]
                                             uint8_t*  __restrict__ cnt8,   // [nbuck][nchunks]
                                             uint32_t* __restrict__ ovf,    // [llen]
                                             int n, int nbuck, int nchunks) {
    extern __shared__ uint16_t srt[];          // nbuck*SLOT u16
    __shared__ uint32_t cur[NBUCK_MAX];
    int tid = threadIdx.x, bk = blockIdx.x;
    int base = bk * CHUNK;
    int m = min(CHUNK, n - base);

    for (int b = tid; b < nbuck; b += 512) cur[b] = (uint32_t)b * SLOT;
    __syncthreads();

    const int4* l4 = (const int4*)(labels + base);
    int k4n = m >> 2;
    for (int k = tid; k < k4n; k += 512) {
        int4 q = l4[k];
        uint32_t v0 = (uint32_t)q.x, v1 = (uint32_t)q.y;
        uint32_t v2 = (uint32_t)q.z, v3 = (uint32_t)q.w;
        uint32_t b0 = v0 >> FBITS, b1 = v1 >> FBITS, b2 = v2 >> FBITS, b3 = v3 >> FBITS;
        uint32_t p0 = atomicAdd(&cur[b0], 1u);
        uint32_t p1 = atomicAdd(&cur[b1], 1u);
        uint32_t p2 = atomicAdd(&cur[b2], 1u);
        uint32_t p3 = atomicAdd(&cur[b3], 1u);
        if (p0 < (b0 + 1u) * SLOT) srt[p0] = (uint16_t)(v0 & (FW - 1)); else atomicAdd(&ovf[v0], 1u);
        if (p1 < (b1 + 1u) * SLOT) srt[p1] = (uint16_t)(v1 & (FW - 1)); else atomicAdd(&ovf[v1], 1u);
        if (p2 < (b2 + 1u) * SLOT) srt[p2] = (uint16_t)(v2 & (FW - 1)); else atomicAdd(&ovf[v2], 1u);
        if (p3 < (b3 + 1u) * SLOT) srt[p3] = (uint16_t)(v3 & (FW - 1)); else atomicAdd(&ovf[v3], 1u);
    }
    for (int i = (k4n << 2) + tid; i < m; i += 512) {
        uint32_t v = (uint32_t)labels[base + i];
        uint32_t b = v >> FBITS;
        uint32_t p = atomicAdd(&cur[b], 1u);
        if (p < (b + 1u) * SLOT) srt[p] = (uint16_t)(v & (FW - 1)); else atomicAdd(&ovf[v], 1u);
    }
    __syncthreads();

    // coalesced write-out of the fixed-stride region (garbage past each
    // cursor is never read: p4a_fs bounds by cnt8)
    int4* dst = (int4*)(sorted + (size_t)bk * nbuck * SLOT);
    const int4* src = (const int4*)srt;
    int nv = nbuck * (SLOT * 2 / 16);
    for (int k = tid; k < nv; k += 512) dst[k] = src[k];
    for (int b = tid; b < nbuck; b += 512) {
        uint32_t c = cur[b] - (uint32_t)b * SLOT;
        cnt8[(size_t)b * nchunks + bk] = (uint8_t)min(c, (uint32_t)SLOT);
    }
}

// p4a_fs: per-(bucket, chunk-range) fine histogram over fixed-stride cells.
// u32-paired reads, LDS atomics, u8 partials. Also writes the winner marker
// (plain store, last-writer-wins; covers every in-image slot).
__global__ __launch_bounds__(256) void p4a_fs(const uint16_t* __restrict__ sorted,
                                              const uint8_t* __restrict__ cnt8,
                                              uint8_t* __restrict__ partials, // [nbuck*SPLIT][FW]
                                              const int* __restrict__ gdict,
                                              uint32_t* __restrict__ marker,  // [nbins]
                                              int llen, int nbins,
                                              int nchunks, int nbuck, int cpb) {
    __shared__ uint32_t h[FW];          // 16 KB
    __shared__ uint8_t cn[SE_MAX];
    int tid = threadIdx.x;

    for (int l = blockIdx.x * 256 + tid; l < llen; l += gridDim.x * 256) {
        uint32_t g = (uint32_t)gdict[l];
        if (g < (uint32_t)nbins) marker[g] = (uint32_t)l + 1u;
    }

    int B = blockIdx.x / SPLIT;
    int k = blockIdx.x % SPLIT;
    for (int j = tid; j < FW; j += 256) h[j] = 0;

    int c0 = k * cpb;
    int c1 = min(c0 + cpb, nchunks);
    int m = c1 - c0;
    for (int t = tid; t < m; t += 256)
        cn[t] = cnt8[(size_t)B * nchunks + c0 + t];   // bucket-major: coalesced
    __syncthreads();

    int wave = tid >> 6, lane = tid & 63;
    int e0 = 2 * lane;
    int u = wave;
    for (; u + 4 < m; u += 8) {
        int lA = cn[u], lB = cn[u + 4];
        const uint32_t* sA = (const uint32_t*)(sorted + ((size_t)(c0 + u) * nbuck + B) * SLOT);
        const uint32_t* sB = (const uint32_t*)(sorted + ((size_t)(c0 + u + 4) * nbuck + B) * SLOT);
        uint32_t wA = 0, wB = 0;
        bool aA = e0 < lA, aB = e0 < lB;
        if (aA) wA = sA[lane];
        if (aB) wB = sB[lane];
        if (aA) { atomicAdd(&h[wA & 0xFFFFu], 1u); if (e0 + 1 < lA) atomicAdd(&h[wA >> 16], 1u); }
        if (aB) { atomicAdd(&h[wB & 0xFFFFu], 1u); if (e0 + 1 < lB) atomicAdd(&h[wB >> 16], 1u); }
    }
    for (; u < m; u += 4) {
        int len = cn[u];
        const uint32_t* s = (const uint32_t*)(sorted + ((size_t)(c0 + u) * nbuck + B) * SLOT);
        if (e0 < len) {
            uint32_t w = s[lane];
            atomicAdd(&h[w & 0xFFFFu], 1u);
            if (e0 + 1 < len) atomicAdd(&h[w >> 16], 1u);
        }
    }
    __syncthreads();

    uint8_t* dst = partials + (size_t)blockIdx.x * FW;
    for (int j = tid; j < FW; j += 256) dst[j] = (uint8_t)h[j];
}

// k3: per-label total (+rare overflow); losers fold into slotsum (device
// atomics only on actually-colliding gdict entries; zero when injective).
__global__ __launch_bounds__(256) void k3_fold(const uint8_t* __restrict__ partials,
                                               const uint32_t* __restrict__ ovf,
                                               const int* __restrict__ gdict,
                                               const uint32_t* __restrict__ marker,
                                               uint32_t* __restrict__ ltot,      // [llen]
                                               uint8_t* __restrict__ conflicted, // [nbins]
                                               uint32_t* __restrict__ slotsum,   // [nbins]
                                               int llen, int nbins) {
    int l = blockIdx.x * 256 + threadIdx.x;
    if (l >= llen) return;
    int B = l >> FBITS;
    int j = l & (FW - 1);
    const uint8_t* p = partials + (size_t)B * SPLIT * FW + j;
    uint32_t sum = ovf[l];
    #pragma unroll
    for (int k = 0; k < SPLIT; ++k) sum += p[(size_t)k * FW];
    ltot[l] = sum;
    uint32_t g = (uint32_t)gdict[l];
    if (g < (uint32_t)nbins && marker[g] != (uint32_t)l + 1u) {
        conflicted[g] = 1;                    // benign same-value race
        atomicAdd(&slotsum[g], sum);          // losers only
    }
}

// k5: epilogue. Unconflicted slot -> unique contributor is i itself;
// conflicted -> losers' slotsum + winner's ltot (order-independent total).
__global__ __launch_bounds__(256) void k5_out(const int* __restrict__ gdict,
                                              const float* __restrict__ cnts,
                                              const uint32_t* __restrict__ ltot,
                                              const uint8_t* __restrict__ conflicted,
                                              const uint32_t* __restrict__ slotsum,
                                              const uint32_t* __restrict__ marker,
                                              const float* __restrict__ total,
                                              float* __restrict__ out,
                                              int llen, int nbins, float nf) {
    int i = blockIdx.x * 256 + threadIdx.x;
    if (i >= llen) return;
    uint32_t g = (uint32_t)gdict[i];
    float c = 0.0f;
    if (g < (uint32_t)nbins) {
        uint32_t v = conflicted[g] ? (slotsum[g] + ltot[marker[g] - 1u]) : ltot[i];
        c = cnts[g] + (float)v;
    }
    out[i] = fmaxf(c / (total[0] + nf), 0.01f);
}

// ======================= tier-2: proven round-5 path =======================

#define PA_T 512
#define PER_T (CHUNK / PA_T)

__global__ __launch_bounds__(PA_T) void pa_sort(const int* __restrict__ labels,
                                                uint32_t* __restrict__ cstart,
                                                uint16_t* __restrict__ sorted,
                                                int n, int nbuck) {
    __shared__ uint16_t srt[CHUNK];
    __shared__ uint32_t cnt[256];
    __shared__ uint32_t scan[PA_T];
    __shared__ uint32_t cur[257];
    int tid = threadIdx.x, bk = blockIdx.x;
    int base = bk * CHUNK;
    uint32_t v[PER_T];
    if (tid < 256) cnt[tid] = 0;
    __syncthreads();
    int tb = base + tid * PER_T;
    if (tb + PER_T <= n) {
        const int4* l4 = (const int4*)(labels + tb);
        #pragma unroll
        for (int i = 0; i < PER_T / 4; ++i) {
            int4 q = l4[i];
            v[4*i+0] = (uint32_t)q.x; v[4*i+1] = (uint32_t)q.y;
            v[4*i+2] = (uint32_t)q.z; v[4*i+3] = (uint32_t)q.w;
        }
        #pragma unroll
        for (int i = 0; i < PER_T; ++i) atomicAdd(&cnt[v[i] >> FBITS], 1u);
    } else {
        for (int i = 0; i < PER_T; ++i) {
            int idx = tb + i;
            if (idx < n) { v[i] = (uint32_t)labels[idx]; atomicAdd(&cnt[v[i] >> FBITS], 1u); }
            else v[i] = 0xFFFFFFFFu;
        }
    }
    __syncthreads();
    uint32_t c = (tid < 256) ? cnt[tid] : 0u;
    scan[tid] = c;
    __syncthreads();
    for (int d = 1; d < 256; d <<= 1) {
        uint32_t add = (tid >= d) ? scan[tid - d] : 0u;
        __syncthreads();
        scan[tid] += add;
        __syncthreads();
    }
    if (tid < 256) cur[tid] = scan[tid] - c;
    if (tid == 255) cur[256] = scan[255];
    __syncthreads();
    for (int i = tid; i < nbuck + 1; i += PA_T)
        cstart[(size_t)bk * (nbuck + 1) + i] = cur[i];
    __syncthreads();
    #pragma unroll
    for (int i = 0; i < PER_T; ++i) {
        uint32_t val = v[i];
        if (val != 0xFFFFFFFFu) {
            uint32_t p = atomicAdd(&cur[val >> FBITS], 1u);
            srt[p] = (uint16_t)(val & (FW - 1));
        }
    }
    __syncthreads();
    int4* dst = (int4*)(sorted + (size_t)bk * CHUNK);
    const int4* src = (const int4*)srt;
    for (int k = tid; k < (CHUNK * 2) / 16; k += PA_T) dst[k] = src[k];
}

__global__ __launch_bounds__(256) void p4a_c(const uint16_t* __restrict__ sorted,
                                             const uint32_t* __restrict__ cstart,
                                             uint8_t* __restrict__ partials,
                                             int nchunks, int nbuck, int cpb) {
    __shared__ uint32_t h[FW];
    __shared__ uint32_t se0[SE_MAX];
    __shared__ uint32_t se1[SE_MAX];
    int tid = threadIdx.x;
    int B = blockIdx.x / SPLIT;
    int k = blockIdx.x % SPLIT;
    for (int j = tid; j < FW; j += 256) h[j] = 0;
    int c0 = k * cpb, c1 = min(c0 + cpb, nchunks), m = c1 - c0;
    for (int t = tid; t < m; t += 256) {
        const uint32_t* row = cstart + (size_t)(c0 + t) * (nbuck + 1);
        se0[t] = row[B]; se1[t] = row[B + 1];
    }
    __syncthreads();
    int wave = tid >> 6, lane = tid & 63;
    int u = wave;
    for (; u + 4 < m; u += 8) {
        uint32_t sA = se0[u], eA = se1[u], sB = se0[u+4], eB = se1[u+4];
        const uint16_t* segA = sorted + (size_t)(c0 + u) * CHUNK;
        const uint16_t* segB = sorted + (size_t)(c0 + u + 4) * CHUNK;
        uint32_t iA = sA + lane, iB = sB + lane;
        uint16_t vA = 0, vB = 0;
        bool okA = iA < eA, okB = iB < eB;
        if (okA) vA = segA[iA];
        if (okB) vB = segB[iB];
        if (okA) atomicAdd(&h[vA], 1u);
        if (okB) atomicAdd(&h[vB], 1u);
        for (iA += 64; iA < eA; iA += 64) atomicAdd(&h[segA[iA]], 1u);
        for (iB += 64; iB < eB; iB += 64) atomicAdd(&h[segB[iB]], 1u);
    }
    for (; u < m; u += 4) {
        uint32_t s = se0[u], e = se1[u];
        const uint16_t* seg = sorted + (size_t)(c0 + u) * CHUNK;
        for (uint32_t i = s + lane; i < e; i += 64) atomicAdd(&h[seg[i]], 1u);
    }
    __syncthreads();
    uint8_t* dst = partials + (size_t)blockIdx.x * FW;
    for (int j = tid; j < FW; j += 256) dst[j] = (uint8_t)h[j];
}

__global__ __launch_bounds__(256) void p4b(const uint8_t* __restrict__ partials,
                                           const int* __restrict__ gdict,
                                           uint32_t* __restrict__ slotsum,
                                           int llen, int nbins) {
    int l = blockIdx.x * 256 + threadIdx.x;
    if (l >= llen) return;
    int B = l >> FBITS;
    int j = l & (FW - 1);
    const uint8_t* p = partials + (size_t)B * SPLIT * FW + j;
    uint32_t sum = 0;
    #pragma unroll
    for (int k = 0; k < SPLIT; ++k) sum += p[(size_t)k * FW];
    if (sum) {
        uint32_t g = (uint32_t)gdict[l];
        if (g < (uint32_t)nbins) atomicAdd(&slotsum[g], sum);
    }
}

__global__ __launch_bounds__(256) void p5_simple(const int* __restrict__ gdict,
                                                 const float* __restrict__ cnts,
                                                 const uint32_t* __restrict__ slotsum,
                                                 const float* __restrict__ total,
                                                 float* __restrict__ out, int llen, float nf) {
    int i = blockIdx.x * 256 + threadIdx.x;
    if (i < llen) {
        uint32_t g = (uint32_t)gdict[i];
        float c = cnts[g] + (float)slotsum[g];
        out[i] = fmaxf(c / (total[0] + nf), 0.01f);
    }
}

// ======================= tier-3: direct atomics =======================
__global__ void hist_atomic(const int* __restrict__ labels,
                            const int* __restrict__ gdict,
                            unsigned int* __restrict__ ws, int n) {
    int tid = blockIdx.x * blockDim.x + threadIdx.x;
    int stride = gridDim.x * blockDim.x;
    int n4 = n >> 2;
    const int4* l4 = (const int4*)labels;
    for (int i = tid; i < n4; i += stride) {
        int4 v = l4[i];
        atomicAdd(&ws[gdict[v.x]], 1u);
        atomicAdd(&ws[gdict[v.y]], 1u);
        atomicAdd(&ws[gdict[v.z]], 1u);
        atomicAdd(&ws[gdict[v.w]], 1u);
    }
    for (int i = (n4 << 2) + tid; i < n; i += stride)
        atomicAdd(&ws[gdict[labels[i]]], 1u);
}

extern "C" void kernel_launch(void* const* d_in, const int* in_sizes, int n_in,
                              void* d_out, int out_size, void* d_ws, size_t ws_size,
                              hipStream_t stream) {
    const int* gdict   = (const int*)d_in[0];
    const int* labels  = (const int*)d_in[1];
    const float* cnts  = (const float*)d_in[3];
    const float* total = (const float*)d_in[4];
    float* out = (float*)d_out;

    int llen  = in_sizes[0];
    int n     = in_sizes[1];
    int nbins = in_sizes[3];

    int nchunks = (n + CHUNK - 1) / CHUNK;
    int nbuck   = (llen + FW - 1) >> FBITS;
    int cpb     = (nchunks + SPLIT - 1) / SPLIT;

    uint8_t* ws8 = (uint8_t*)d_ws;

    // ---- v6 layout: [zeroed: slotsum|conflicted|ovf][marker][ltot][cnt8][sorted][partials]
    size_t o_slot = 0;
    size_t o_conf = align256(o_slot + (size_t)nbins * 4);
    size_t o_ovf  = align256(o_conf + (size_t)nbins);
    size_t z_end  = align256(o_ovf  + (size_t)llen * 4);     // zero [0, z_end)
    size_t o_mark = z_end;                                    // NOT zeroed (see p4a_fs)
    size_t o_ltot = align256(o_mark + (size_t)nbins * 4);
    size_t o_cnt  = align256(o_ltot + (size_t)llen * 4);
    size_t o_srt  = align256(o_cnt  + (size_t)nbuck * nchunks);
    size_t o_part = align256(o_srt  + (size_t)nchunks * nbuck * SLOT * 2);
    size_t need6  = o_part + (size_t)nbuck * SPLIT * FW;

    // ---- tier-2 layout ----
    size_t t_slot = 0;
    size_t t_cst  = align256((size_t)nbins * 4);
    size_t t_srt  = align256(t_cst + (size_t)nchunks * (nbuck + 1) * 4);
    size_t t_part = align256(t_srt + (size_t)nchunks * CHUNK * 2);
    size_t need5  = t_part + (size_t)nbuck * SPLIT * FW;

    size_t lds_fs = (size_t)nbuck * SLOT * 2;

    if (nbuck <= NBUCK_MAX && cpb <= SE_MAX && need6 <= ws_size && lds_fs <= 64 * 1024) {
        uint32_t* slotsum    = (uint32_t*)(ws8 + o_slot);
        uint8_t*  conflicted = (uint8_t*)(ws8 + o_conf);
        uint32_t* ovf        = (uint32_t*)(ws8 + o_ovf);
        uint32_t* marker     = (uint32_t*)(ws8 + o_mark);
        uint32_t* ltot       = (uint32_t*)(ws8 + o_ltot);
        uint8_t*  cnt8       = (uint8_t*)(ws8 + o_cnt);
        uint16_t* sorted     = (uint16_t*)(ws8 + o_srt);
        uint8_t*  partials   = (uint8_t*)(ws8 + o_part);

        int zn16 = (int)(z_end / 16);
        hipLaunchKernelGGL(zero_ws, dim3(1024), dim3(256), 0, stream,
                           (int4*)ws8, zn16);
        hipLaunchKernelGGL(pa_fs, dim3(nchunks), dim3(512), lds_fs, stream,
                           labels, sorted, cnt8, ovf, n, nbuck, nchunks);
        hipLaunchKernelGGL(p4a_fs, dim3(nbuck * SPLIT), dim3(256), 0, stream,
                           sorted, cnt8, partials, gdict, marker,
                           llen, nbins, nchunks, nbuck, cpb);
        hipLaunchKernelGGL(k3_fold, dim3((llen + 255) / 256), dim3(256), 0, stream,
                           partials, ovf, gdict, marker, ltot, conflicted, slotsum,
                           llen, nbins);
        hipLaunchKernelGGL(k5_out, dim3((llen + 255) / 256), dim3(256), 0, stream,
                           gdict, cnts, ltot, conflicted, slotsum, marker, total,
                           out, llen, nbins, (float)n);
    } else if (nbuck <= 256 && cpb <= SE_MAX && need5 <= ws_size) {
        uint32_t* slotsum  = (uint32_t*)(ws8 + t_slot);
        uint32_t* cstart   = (uint32_t*)(ws8 + t_cst);
        uint16_t* sorted   = (uint16_t*)(ws8 + t_srt);
        uint8_t*  partials = (uint8_t*)(ws8 + t_part);

        hipMemsetAsync(slotsum, 0, (size_t)nbins * 4, stream);
        hipLaunchKernelGGL(pa_sort, dim3(nchunks), dim3(PA_T), 0, stream,
                           labels, cstart, sorted, n, nbuck);
        hipLaunchKernelGGL(p4a_c, dim3(nbuck * SPLIT), dim3(256), 0, stream,
                           sorted, cstart, partials, nchunks, nbuck, cpb);
        hipLaunchKernelGGL(p4b, dim3((llen + 255) / 256), dim3(256), 0, stream,
                           partials, gdict, slotsum, llen, nbins);
        hipLaunchKernelGGL(p5_simple, dim3((llen + 255) / 256), dim3(256), 0, stream,
                           gdict, cnts, slotsum, total, out, llen, (float)n);
    } else {
        uint32_t* slotsum = (uint32_t*)ws8;
        hipMemsetAsync(slotsum, 0, (size_t)nbins * 4, stream);
        hipLaunchKernelGGL(hist_atomic, dim3(2048), dim3(256), 0, stream,
                           labels, gdict, (unsigned int*)slotsum, n);
        hipLaunchKernelGGL(p5_simple, dim3((llen + 255) / 256), dim3(256), 0, stream,
                           gdict, cnts, slotsum, total, out, llen, (float)n);
    }
}

// Round 10
// 34.060 us; speedup vs baseline: 19.1183x; 1.5702x over previous
//
#include <hip/hip_runtime.h>
#include <stdint.h>

// out[i] = max((cnts[g_i] + h[g_i]) / (total + N), 0.01),
//   g_i = gdict[i], h[s] = #{ t : gdict[flatten_label[t]] == s }.
//
// Structural shortcut (exact, data-dependent): the clip floor 0.01*T needs
// ~167K counts in ONE slot (5000x the 33.5 mean). Per coarse bucket B(l)=l>>12,
// h[gdict[l]] <= bucket_count[B(l)] when gdict is injective at that slot. fp
// add/div are monotone, so (cnts+ub)/T <= 0.01 => (cnts+h)/T <= 0.01 => out is
// EXACTLY 0.01. One coarse pass (123 LDS counters) decides everything; a
// flag-gated exact fallback (always launched, no-op when all slots decided or
// no gdict collisions) keeps correctness for arbitrary inputs.
//
// gfx950 facts (measured rounds 1/6): global atomics are memory-side
// write-through (~32B each) at ANY scope -> fallback only. LDS atomics ~2/cyc/CU;
// REPL=4 sub-histograms cut intra-wave same-address replays.

#define FBITS     12
#define NBUCK_MAX 256
#define REPL      4
#define GRID_A    2048

static inline size_t align256(size_t x) { return (x + 255) & ~(size_t)255; }

// ---- zero: grid-stride int4 ----
__global__ __launch_bounds__(256) void zero_ws(int4* __restrict__ p, int n16) {
    int tid = blockIdx.x * 256 + threadIdx.x;
    int stride = gridDim.x * 256;
    int4 z = {0, 0, 0, 0};
    for (int i = tid; i < n16; i += stride) p[i] = z;
}

// ---- kA: coarse label-bucket histogram (REPL LDS sub-copies) + winner marker ----
__global__ __launch_bounds__(256) void kA_coarse(const int* __restrict__ labels,
                                                 const int* __restrict__ gdict,
                                                 uint32_t* __restrict__ pbc,    // [GRID_A][nbuck]
                                                 uint32_t* __restrict__ marker, // [nbins] (not zeroed)
                                                 int n, int llen, int nbins, int nbuck) {
    __shared__ uint32_t h[REPL * NBUCK_MAX];   // 4 KB
    int tid = threadIdx.x, bk = blockIdx.x;
    int gstride = gridDim.x * 256;

    // winner marking: every in-image slot gets rewritten each call
    for (int l = bk * 256 + tid; l < llen; l += gstride) {
        uint32_t g = (uint32_t)gdict[l];
        if (g < (uint32_t)nbins) marker[g] = (uint32_t)l + 1u;
    }

    for (int j = tid; j < REPL * nbuck; j += 256) h[j] = 0;
    __syncthreads();

    int r = tid & (REPL - 1);
    const int4* l4 = (const int4*)labels;
    int n4 = n >> 2;
    for (int i = bk * 256 + tid; i < n4; i += gstride) {
        int4 q = l4[i];
        atomicAdd(&h[(((uint32_t)q.x) >> FBITS) * REPL + r], 1u);
        atomicAdd(&h[(((uint32_t)q.y) >> FBITS) * REPL + r], 1u);
        atomicAdd(&h[(((uint32_t)q.z) >> FBITS) * REPL + r], 1u);
        atomicAdd(&h[(((uint32_t)q.w) >> FBITS) * REPL + r], 1u);
    }
    for (int i = (n4 << 2) + bk * 256 + tid; i < n; i += gstride)
        atomicAdd(&h[(((uint32_t)labels[i]) >> FBITS) * REPL + r], 1u);
    __syncthreads();

    for (int b = tid; b < nbuck; b += 256)
        pbc[(size_t)bk * nbuck + b] =
            h[b * REPL] + h[b * REPL + 1] + h[b * REPL + 2] + h[b * REPL + 3];
}

// ---- kB: reduce per-block coarse counts -> bc[nbuck] ----
__global__ __launch_bounds__(256) void kB_reduce(const uint32_t* __restrict__ pbc,
                                                 uint32_t* __restrict__ bc,
                                                 int nblocks, int nbuck) {
    __shared__ uint32_t wsum[4];
    int b = blockIdx.x, tid = threadIdx.x;
    uint32_t s = 0;
    for (int j = tid; j < nblocks; j += 256) s += pbc[(size_t)j * nbuck + b];
    for (int o = 32; o > 0; o >>= 1) s += __shfl_down(s, o, 64);
    if ((tid & 63) == 0) wsum[tid >> 6] = s;
    __syncthreads();
    if (tid == 0) bc[b] = wsum[0] + wsum[1] + wsum[2] + wsum[3];
}

// ---- kC: conflict detection (losers mark; benign same-value race) ----
__global__ __launch_bounds__(256) void kC_conf(const int* __restrict__ gdict,
                                               const uint32_t* __restrict__ marker,
                                               uint8_t* __restrict__ conflicted,
                                               int llen, int nbins) {
    int l = blockIdx.x * 256 + threadIdx.x;
    if (l >= llen) return;
    uint32_t g = (uint32_t)gdict[l];
    if (g < (uint32_t)nbins && marker[g] != (uint32_t)l + 1u) conflicted[g] = 1;
}

// ---- kD: decide via upper bound; undecided slots raise the exact flag ----
__global__ __launch_bounds__(256) void kD_decide(const int* __restrict__ gdict,
                                                 const float* __restrict__ cnts,
                                                 const uint32_t* __restrict__ bc,
                                                 const uint8_t* __restrict__ conflicted,
                                                 const float* __restrict__ total,
                                                 float* __restrict__ out,
                                                 uint32_t* __restrict__ flag,
                                                 int llen, int nbins, float nf) {
    int i = blockIdx.x * 256 + threadIdx.x;
    if (i >= llen) return;
    int gi = gdict[i];
    uint32_t g = (uint32_t)min(max(gi, 0), nbins - 1);   // jax-style clamp
    float T = total[0] + nf;
    float v = (cnts[g] + (float)bc[i >> FBITS]) / T;
    bool dec = ((uint32_t)gi < (uint32_t)nbins) && (!conflicted[g]) && (v <= 0.01f);
    if (dec) out[i] = 0.01f;
    else     atomicOr(flag, 1u);   // rare: trips the exact fallback
}

// ---- guarded exact fallback: full device-atomic histogram (runs only if flag) ----
__global__ void histG(const uint32_t* __restrict__ flag,
                      const int* __restrict__ labels,
                      const int* __restrict__ gdict,
                      unsigned int* __restrict__ slotsum, int n, int nbins) {
    if (*flag == 0u) return;
    int tid = blockIdx.x * blockDim.x + threadIdx.x;
    int stride = gridDim.x * blockDim.x;
    int n4 = n >> 2;
    const int4* l4 = (const int4*)labels;
    for (int i = tid; i < n4; i += stride) {
        int4 v = l4[i];
        uint32_t g0 = (uint32_t)gdict[v.x], g1 = (uint32_t)gdict[v.y];
        uint32_t g2 = (uint32_t)gdict[v.z], g3 = (uint32_t)gdict[v.w];
        if (g0 < (uint32_t)nbins) atomicAdd(&slotsum[g0], 1u);
        if (g1 < (uint32_t)nbins) atomicAdd(&slotsum[g1], 1u);
        if (g2 < (uint32_t)nbins) atomicAdd(&slotsum[g2], 1u);
        if (g3 < (uint32_t)nbins) atomicAdd(&slotsum[g3], 1u);
    }
    for (int i = (n4 << 2) + tid; i < n; i += stride) {
        uint32_t g = (uint32_t)gdict[labels[i]];
        if (g < (uint32_t)nbins) atomicAdd(&slotsum[g], 1u);
    }
}

__global__ __launch_bounds__(256) void p5G(const uint32_t* __restrict__ flag,
                                           const int* __restrict__ gdict,
                                           const float* __restrict__ cnts,
                                           const uint32_t* __restrict__ slotsum,
                                           const float* __restrict__ total,
                                           float* __restrict__ out,
                                           int llen, int nbins, float nf) {
    if (*flag == 0u) return;
    int i = blockIdx.x * 256 + threadIdx.x;
    if (i >= llen) return;
    int gi = gdict[i];
    uint32_t g = (uint32_t)min(max(gi, 0), nbins - 1);
    out[i] = fmaxf((cnts[g] + (float)slotsum[g]) / (total[0] + nf), 0.01f);
}

// ---- tier-3: unconditional exact path (tiny ws / huge nbuck) ----
__global__ void hist_atomic(const int* __restrict__ labels,
                            const int* __restrict__ gdict,
                            unsigned int* __restrict__ ws, int n, int nbins) {
    int tid = blockIdx.x * blockDim.x + threadIdx.x;
    int stride = gridDim.x * blockDim.x;
    for (int i = tid; i < n; i += stride) {
        uint32_t g = (uint32_t)gdict[labels[i]];
        if (g < (uint32_t)nbins) atomicAdd(&ws[g], 1u);
    }
}

__global__ __launch_bounds__(256) void p5_simple(const int* __restrict__ gdict,
                                                 const float* __restrict__ cnts,
                                                 const uint32_t* __restrict__ slotsum,
                                                 const float* __restrict__ total,
                                                 float* __restrict__ out,
                                                 int llen, int nbins, float nf) {
    int i = blockIdx.x * 256 + threadIdx.x;
    if (i < llen) {
        int gi = gdict[i];
        uint32_t g = (uint32_t)min(max(gi, 0), nbins - 1);
        out[i] = fmaxf((cnts[g] + (float)slotsum[g]) / (total[0] + nf), 0.01f);
    }
}

extern "C" void kernel_launch(void* const* d_in, const int* in_sizes, int n_in,
                              void* d_out, int out_size, void* d_ws, size_t ws_size,
                              hipStream_t stream) {
    const int* gdict   = (const int*)d_in[0];
    const int* labels  = (const int*)d_in[1];
    const float* cnts  = (const float*)d_in[3];
    const float* total = (const float*)d_in[4];
    float* out = (float*)d_out;

    int llen  = in_sizes[0];
    int n     = in_sizes[1];
    int nbins = in_sizes[3];
    int nbuck = ((llen - 1) >> FBITS) + 1;

    uint8_t* ws8 = (uint8_t*)d_ws;

    // layout: [zeroed: flag | bc | conflicted | slotsum] [marker] [pbc]
    size_t o_flag = 0;
    size_t o_bc   = 256;
    size_t o_conf = align256(o_bc + (size_t)nbuck * 4);
    size_t o_slot = align256(o_conf + (size_t)nbins);
    size_t z_end  = align256(o_slot + (size_t)nbins * 4);    // zero [0, z_end)
    size_t o_mark = z_end;                                    // NOT zeroed
    size_t o_pbc  = align256(o_mark + (size_t)nbins * 4);     // NOT zeroed (fully written)
    size_t needed = o_pbc + (size_t)GRID_A * nbuck * 4;

    if (nbuck <= NBUCK_MAX && needed <= ws_size) {
        uint32_t* flag       = (uint32_t*)(ws8 + o_flag);
        uint32_t* bc         = (uint32_t*)(ws8 + o_bc);
        uint8_t*  conflicted = (uint8_t*)(ws8 + o_conf);
        uint32_t* slotsum    = (uint32_t*)(ws8 + o_slot);
        uint32_t* marker     = (uint32_t*)(ws8 + o_mark);
        uint32_t* pbc        = (uint32_t*)(ws8 + o_pbc);

        int lblocks = (llen + 255) / 256;

        hipLaunchKernelGGL(zero_ws, dim3(1024), dim3(256), 0, stream,
                           (int4*)ws8, (int)(z_end / 16));
        hipLaunchKernelGGL(kA_coarse, dim3(GRID_A), dim3(256), 0, stream,
                           labels, gdict, pbc, marker, n, llen, nbins, nbuck);
        hipLaunchKernelGGL(kB_reduce, dim3(nbuck), dim3(256), 0, stream,
                           pbc, bc, GRID_A, nbuck);
        hipLaunchKernelGGL(kC_conf, dim3(lblocks), dim3(256), 0, stream,
                           gdict, marker, conflicted, llen, nbins);
        hipLaunchKernelGGL(kD_decide, dim3(lblocks), dim3(256), 0, stream,
                           gdict, cnts, bc, conflicted, total, out, flag,
                           llen, nbins, (float)n);
        hipLaunchKernelGGL(histG, dim3(2048), dim3(256), 0, stream,
                           flag, labels, gdict, (unsigned int*)slotsum, n, nbins);
        hipLaunchKernelGGL(p5G, dim3(lblocks), dim3(256), 0, stream,
                           flag, gdict, cnts, slotsum, total, out, llen, nbins, (float)n);
    } else {
        uint32_t* slotsum = (uint32_t*)ws8;
        hipMemsetAsync(slotsum, 0, (size_t)nbins * 4, stream);
        hipLaunchKernelGGL(hist_atomic, dim3(2048), dim3(256), 0, stream,
                           labels, gdict, (unsigned int*)slotsum, n, nbins);
        hipLaunchKernelGGL(p5_simple, dim3((llen + 255) / 256), dim3(256), 0, stream,
                           gdict, cnts, slotsum, total, out, llen, nbins, (float)n);
    }
}